// Round 6
// baseline (14611.320 us; speedup 1.0000x reference)
//
#include <hip/hip_runtime.h>
#include <hip/hip_bf16.h>
#include <math.h>

typedef __bf16 bf16_t;
typedef __bf16 bf16x8 __attribute__((ext_vector_type(8)));
typedef float  f32x4  __attribute__((ext_vector_type(4)));
typedef unsigned int  uint32;
typedef unsigned short ushort16;

// ---------------- workspace layout (bytes) ----------------
#define WS_WSP    0        // 1297 f32
#define WS_AH     5248     // 256 f32
#define WS_U527   6272     // 527 f32
#define WS_BIAS   8384     // 1 f32
#define WS_BIASG  8448     // 1024 f32
#define WS_WC     12544    // 655360 B fragment-swizzled weights
#define WS_FLAGS  667904   // 64*4 int flags
#define WS_HBUF   669184   // 2*64*4*16384 bf16 = 16 MB h exchange (swizzled slices)

__device__ __forceinline__ float sigmoidf_fast(float x) {
    return 1.f / (1.f + __expf(-x));
}
__device__ __forceinline__ float tanhf_fast(float x) {
    return 1.f - 2.f / (1.f + __expf(2.f * x));
}

// ---------------- head/spatial weight composition (tiny) ----------------
__global__ void k_head(const float* __restrict__ sl_w, const float* __restrict__ sl_b,
                       const float* __restrict__ st_w, const float* __restrict__ st_b,
                       const float* __restrict__ seg_b,
                       const float* __restrict__ l1_w, const float* __restrict__ l1_b,
                       const float* __restrict__ l2_w, const float* __restrict__ l2_b,
                       const float* __restrict__ l4_w, const float* __restrict__ l4_b,
                       const float* __restrict__ l5_w, const float* __restrict__ l5_b,
                       const float* __restrict__ l6_w, const float* __restrict__ l6_b,
                       const float* __restrict__ l7_w, const float* __restrict__ l7_b,
                       float* __restrict__ wsp, float* __restrict__ ah,
                       float* __restrict__ u527_out, float* __restrict__ bias_out) {
    __shared__ float v2[128], v3[256], aa[384], u256[256], u527[527];
    __shared__ float red[8];
    const int t = threadIdx.x;   // 512 threads

    if (t < 128) { float s = 0.f; for (int i = 0; i < 128; ++i) s += l7_w[i] * l6_w[i*128 + t]; v2[t] = s; }
    __syncthreads();
    if (t < 256) { float s = 0.f; for (int i = 0; i < 128; ++i) s += v2[i] * l5_w[i*256 + t]; v3[t] = s; }
    __syncthreads();
    if (t < 384) { float s = 0.f; for (int i = 0; i < 256; ++i) s += v3[i] * l4_w[i*384 + t]; aa[t] = s; }
    __syncthreads();
    if (t < 256) { float s = 0.f; for (int i = 0; i < 128; ++i) s += aa[i] * l2_w[i*256 + t]; u256[t] = s; }
    if (t < 256) ah[t] = aa[128 + t];
    __syncthreads();
    for (int j = t; j < 527; j += 512) {
        float s = 0.f;
        for (int i = 0; i < 256; ++i) s += u256[i] * l1_w[i*527 + j];
        u527[j] = s; u527_out[j] = s;
    }
    __syncthreads();
    if (t < 4)              { float s = 0.f; for (int i = 0; i < 2; ++i) s += u527[i]     * sl_w[i*4  + t];      wsp[t] = s; }
    else if (t < 16)        { int c = t - 4;  float s = 0.f; for (int i = 0; i < 8; ++i) s += u527[2+i] * st_w[i*12 + c]; wsp[t] = s; }
    else if (t < 21)        { wsp[1292 + (t - 16)] = u527[522 + (t - 16)]; }
    float p = 0.f;
    if (t < 128) p += l7_w[t] * l6_b[t] + v2[t] * l5_b[t] + aa[t] * l2_b[t];
    if (t < 256) p += v3[t] * l4_b[t] + u256[t] * l1_b[t];
    if (t < 2)   p += u527[t] * sl_b[t];
    if (t < 8)   p += u527[2 + t] * st_b[t];
    p += u527[10 + t] * seg_b[t];
    p += __shfl_xor(p, 1);  p += __shfl_xor(p, 2);  p += __shfl_xor(p, 4);
    p += __shfl_xor(p, 8);  p += __shfl_xor(p, 16); p += __shfl_xor(p, 32);
    if ((t & 63) == 0) red[t >> 6] = p;
    __syncthreads();
    if (t == 0) {
        float s = l7_b[0];
        for (int i = 0; i < 8; ++i) s += red[i];
        *bias_out = s;
    }
}

__global__ void k_seg(const float* __restrict__ seg_w, const float* __restrict__ u527,
                      float* __restrict__ wsp) {
    int j = blockIdx.x * 256 + threadIdx.x;
    if (j >= 1276) return;
    float s = 0.f;
    for (int i = 0; i < 512; ++i) s += u527[10 + i] * seg_w[i*1276 + j];
    wsp[16 + j] = s;
}

// fragment-swizzled combined weights (same layout as R2..R5)
__global__ void k_wc(const float* __restrict__ w_ih, const float* __restrict__ b_ih,
                     const float* __restrict__ w_hh, const float* __restrict__ b_hh,
                     bf16_t* __restrict__ wc, float* __restrict__ biasg) {
    int idx = blockIdx.x * 256 + threadIdx.x;
    if (idx < 1024) biasg[idx] = b_ih[idx] + b_hh[idx];
    if (idx < 1024 * 320) {
        int e  = idx & 7;
        int l  = (idx >> 3) & 63;
        int t2 = idx >> 9;
        int kk = t2 % 10;
        int nt = t2 / 10;
        int n  = nt * 16 + (l & 15);
        int k  = kk * 32 + ((l >> 4) << 3) + e;
        float v = 0.f;
        if (k < 56)       v = w_ih[n*56 + k];
        else if (k >= 64) v = w_hh[n*256 + (k - 64)];
        wc[idx] = (bf16_t)v;
    }
}

__global__ void k_spatial(const float* __restrict__ sp, const float* __restrict__ wsp,
                          const float* __restrict__ bias, float* __restrict__ out) {
    int row  = blockIdx.x * 4 + (threadIdx.x >> 6);
    int lane = threadIdx.x & 63;
    const float* rp = sp + (size_t)row * 1297;
    float s = 0.f;
    for (int k = lane; k < 1297; k += 64) s += rp[k] * wsp[k];
    s += __shfl_xor(s, 1);  s += __shfl_xor(s, 2);  s += __shfl_xor(s, 4);
    s += __shfl_xor(s, 8);  s += __shfl_xor(s, 16); s += __shfl_xor(s, 32);
    if (lane == 0) out[row] = s + bias[0];
}

// ---------------- LSTM v6: AGPR-resident weights, 64 rg x 4 cg, 4 waves ----------------
// Block (rg,cg): rows [rg*256,+256), hidden [cg*64,+64). Wave w owns hd [16w,16w+16)
// for all 4 gates: 40 weight frags pinned in AGPRs (160 regs); acc in AGPRs.
// LDS: Hs[4][256][64] bf16 (h(t-1), XOR-swizzled 16B slots) + Xb[256][64] bf16 (x_t).
// Sibling h exchange via global hbuf (parity double-buffered) + step-stamped flags.
__launch_bounds__(256, 1)
__global__ void k_lstm(const float* __restrict__ temporal, const bf16_t* __restrict__ wc,
                       const float* __restrict__ biasg, const float* __restrict__ ah,
                       bf16_t* __restrict__ hbuf, int* __restrict__ flags,
                       float* __restrict__ out) {
    __shared__ bf16_t Hs[4 * 256 * 64];   // 131072 B
    __shared__ bf16_t Xb[256 * 64];       //  32768 B  (total 160 KiB exactly)
    const int tid  = threadIdx.x;
    const int lane = tid & 63;
    const int w    = tid >> 6;            // 0..3
    const int bid  = blockIdx.x;
    const int cg   = bid >> 6;            // 0..3
    const int rg   = bid & 63;            // 0..63
    const int l15  = lane & 15;
    const int l4q  = lane >> 4;           // 0..3
    const int swzr = l15 & 7;             // row&7 for A-read rows (row = ...*16 + l15)

    // ---- persistent weights in AGPRs: wfr[q][kk], ntile = q*16 + cg*4 + w ----
    f32x4 wfr[4][10];
#pragma unroll
    for (int q = 0; q < 4; ++q)
#pragma unroll
        for (int kk = 0; kk < 10; ++kk) {
            int nt = q*16 + cg*4 + w;
            wfr[q][kk] = *reinterpret_cast<const f32x4*>(wc + ((size_t)(nt*10 + kk)*64 + lane)*8);
        }
#pragma unroll
    for (int q = 0; q < 4; ++q)
#pragma unroll
        for (int kk = 0; kk < 10; ++kk)
            asm volatile("" : "+a"(wfr[q][kk]));   // pin to AGPR class; no remat

    const int hdl = 16*w + l15;           // hidden dim local to block (0..63)
    float bias[4];
#pragma unroll
    for (int q = 0; q < 4; ++q) bias[q] = biasg[q*256 + cg*64 + hdl];
    const float ahv = ah[cg*64 + hdl];

    f32x4 cst[16];                        // c state [p*4+rt][e]
#pragma unroll
    for (int i = 0; i < 16; ++i) cst[i] = (f32x4){0.f,0.f,0.f,0.f};
    uint32 hpk[32];                       // h (bf16 pairs) [ (p*4+rt)*2 + (e>>1) ]

    // ---- prologue: zero LDS, load+convert x(0) ----
    f32x4 xv[14];
    {
        const float* xb0 = temporal + (size_t)(rg*256)*5376;   // t=0
#pragma unroll
        for (int i = 0; i < 14; ++i) {
            int c = i*256 + tid;
            int row = (c*4682) >> 16;
            int j4 = c - row*14;
            xv[i] = *reinterpret_cast<const f32x4*>(xb0 + (size_t)row*5376 + j4*4);
        }
    }
    for (int i = tid; i < 32768; i += 256) reinterpret_cast<uint32*>(Hs)[i] = 0u;
    for (int i = tid; i < 8192;  i += 256) reinterpret_cast<uint32*>(Xb)[i] = 0u;
    {
#pragma unroll
        for (int i = 0; i < 14; ++i) {
            int c = i*256 + tid;
            int row = (c*4682) >> 16;
            int j4 = c - row*14;
            uint32 lo = (uint32)__builtin_bit_cast(unsigned short, (bf16_t)xv[i][0])
                      | ((uint32)__builtin_bit_cast(unsigned short, (bf16_t)xv[i][1]) << 16);
            uint32 hi = (uint32)__builtin_bit_cast(unsigned short, (bf16_t)xv[i][2])
                      | ((uint32)__builtin_bit_cast(unsigned short, (bf16_t)xv[i][3]) << 16);
            char* p = (char*)Xb + row*128 + (((j4>>1) ^ (row&7)) << 4) + (j4&1)*8;
            reinterpret_cast<uint32*>(p)[0] = lo;
            reinterpret_cast<uint32*>(p)[1] = hi;
        }
    }
    __syncthreads();

#pragma unroll 1
    for (int t = 0; t < 96; ++t) {
        // ---- ingest sibling h(t-1) slices ----
        if (t > 0) {
            if (tid < 3) {
                int sl = tid + (tid >= cg ? 1 : 0);
                while (__hip_atomic_load(&flags[rg*4 + sl], __ATOMIC_ACQUIRE,
                                         __HIP_MEMORY_SCOPE_AGENT) < t)
                    __builtin_amdgcn_s_sleep(8);
            }
            __syncthreads();
            int par = (t - 1) & 1;
#pragma unroll
            for (int it = 0; it < 24; ++it) {
                int i = it*256 + tid;                 // 0..6143
                int sl3 = i >> 11;                    // 0..2
                int chunk = i & 2047;                 // 16B chunks within slice
                int cgs = sl3 + (sl3 >= cg ? 1 : 0);
                const bf16_t* src = hbuf + (((size_t)(par*64 + rg)*4 + cgs) << 14) + chunk*8;
                __builtin_amdgcn_global_load_lds(
                    (const __attribute__((address_space(1))) uint32_t*)src,
                    (__attribute__((address_space(3))) uint32_t*)(Hs + (cgs << 14)) + chunk*4,
                    16, 0, 0);
            }
            asm volatile("s_waitcnt vmcnt(0)" ::: "memory");
            __syncthreads();
        }

        // ---- 4 row-passes: MFMA + gates ----
#pragma unroll
        for (int p = 0; p < 4; ++p) {
            f32x4 acc[4][4];
#pragma unroll
            for (int rt = 0; rt < 4; ++rt)
#pragma unroll
                for (int q = 0; q < 4; ++q)
                    acc[rt][q] = (f32x4){bias[q], bias[q], bias[q], bias[q]};

#pragma unroll
            for (int kk = 0; kk < 10; ++kk) {
                bf16x8 af[4];
#pragma unroll
                for (int rt = 0; rt < 4; ++rt) {
                    int row = p*64 + rt*16 + l15;
                    const char* ap;
                    if (kk < 2) {
                        int slot = kk*4 + l4q;
                        ap = (const char*)Xb + row*128 + ((slot ^ swzr) << 4);
                    } else {
                        int hd0 = (kk - 2)*32 + l4q*8;          // 0..255
                        ap = (const char*)Hs + ((hd0 >> 6) << 15)
                           + row*128 + ((((hd0 >> 3) & 7) ^ swzr) << 4);
                    }
                    af[rt] = *reinterpret_cast<const bf16x8*>(ap);
                }
#pragma unroll
                for (int q = 0; q < 4; ++q)
#pragma unroll
                    for (int rt = 0; rt < 4; ++rt)
                        acc[rt][q] = __builtin_amdgcn_mfma_f32_16x16x32_bf16(
                            af[rt], __builtin_bit_cast(bf16x8, wfr[q][kk]), acc[rt][q], 0, 0, 0);
            }

            // gates -> c, h (packed bf16, regs only)
#pragma unroll
            for (int rt = 0; rt < 4; ++rt)
#pragma unroll
                for (int e = 0; e < 4; ++e) {
                    float ig = sigmoidf_fast(acc[rt][0][e]);
                    float fg = sigmoidf_fast(acc[rt][1][e]);
                    float gt = tanhf_fast(acc[rt][2][e]);
                    float og = sigmoidf_fast(acc[rt][3][e]);
                    float cn = fg * cst[p*4+rt][e] + ig * gt;
                    cst[p*4+rt][e] = cn;
                    float hh = og * tanhf_fast(cn);
                    uint32 hb = (uint32)__builtin_bit_cast(unsigned short, (bf16_t)hh);
                    int k = (p*4 + rt)*2 + (e >> 1);
                    hpk[k] = (e & 1) ? (hpk[k] | (hb << 16)) : hb;
                }
        }

        __syncthreads();   // all Hs/Xb reads complete before overwrite

        // ---- issue x(t+1) loads (latency hides under h-write phase) ----
        if (t < 95) {
            const float* xb0 = temporal + (size_t)(rg*256)*5376 + (size_t)(t+1)*56;
#pragma unroll
            for (int i = 0; i < 14; ++i) {
                int c = i*256 + tid;
                int row = (c*4682) >> 16;
                int j4 = c - row*14;
                xv[i] = *reinterpret_cast<const f32x4*>(xb0 + (size_t)row*5376 + j4*4);
            }
        }

        // ---- write h(t): own LDS slice + hbuf (both pre-swizzled, same offsets) ----
        {
            int par = t & 1;
            char* gslice = (char*)(hbuf + (((size_t)(par*64 + rg)*4 + cg) << 14));
            char* lslice = (char*)Hs + (cg << 15);
            const int slotw = (hdl >> 3);
            const int hl2   = (hdl & 7)*2;
#pragma unroll
            for (int p = 0; p < 4; ++p)
#pragma unroll
                for (int rt = 0; rt < 4; ++rt)
#pragma unroll
                    for (int e = 0; e < 4; ++e) {
                        int row = p*64 + rt*16 + l4q*4 + e;
                        int off = row*128 + ((slotw ^ (row & 7)) << 4) + hl2;
                        unsigned short hv =
                            (unsigned short)(hpk[(p*4+rt)*2 + (e>>1)] >> ((e & 1)*16));
                        *reinterpret_cast<unsigned short*>(lslice + off) = hv;
                        *reinterpret_cast<unsigned short*>(gslice + off) = hv;
                    }
        }

        if (t < 95) {
            asm volatile("s_waitcnt vmcnt(0)" ::: "memory");   // x loads + hbuf stores done
            // convert x(t+1) into Xb (post-barrier: no one reads Xb until next step)
#pragma unroll
            for (int i = 0; i < 14; ++i) {
                int c = i*256 + tid;
                int row = (c*4682) >> 16;
                int j4 = c - row*14;
                uint32 lo = (uint32)__builtin_bit_cast(unsigned short, (bf16_t)xv[i][0])
                          | ((uint32)__builtin_bit_cast(unsigned short, (bf16_t)xv[i][1]) << 16);
                uint32 hi = (uint32)__builtin_bit_cast(unsigned short, (bf16_t)xv[i][2])
                          | ((uint32)__builtin_bit_cast(unsigned short, (bf16_t)xv[i][3]) << 16);
                char* p = (char*)Xb + row*128 + (((j4>>1) ^ (row&7)) << 4) + (j4&1)*8;
                reinterpret_cast<uint32*>(p)[0] = lo;
                reinterpret_cast<uint32*>(p)[1] = hi;
            }
            __threadfence();
            __syncthreads();
            if (tid == 0)
                __hip_atomic_store(&flags[rg*4 + cg], t + 1, __ATOMIC_RELEASE,
                                   __HIP_MEMORY_SCOPE_AGENT);
        }
    }

    // ---- epilogue: out[row] += sum_hd ah[hd] * h_T[row][hd] ----
#pragma unroll
    for (int p = 0; p < 4; ++p)
#pragma unroll
        for (int rt = 0; rt < 4; ++rt)
#pragma unroll
            for (int e = 0; e < 4; ++e) {
                uint32 hb = (hpk[(p*4+rt)*2 + (e>>1)] >> ((e & 1)*16)) & 0xffffu;
                float hf = __builtin_bit_cast(float, hb << 16);
                float s = ahv * hf;
                s += __shfl_xor(s, 1); s += __shfl_xor(s, 2);
                s += __shfl_xor(s, 4); s += __shfl_xor(s, 8);
                if (l15 == 0)
                    atomicAdd(&out[rg*256 + p*64 + rt*16 + l4q*4 + e], s);
            }
}

// ---------------- launch ----------------
extern "C" void kernel_launch(void* const* d_in, const int* in_sizes, int n_in,
                              void* d_out, int out_size, void* d_ws, size_t ws_size,
                              hipStream_t stream) {
    const float* spatial  = (const float*)d_in[0];
    const float* temporal = (const float*)d_in[1];
    const float* sl_w = (const float*)d_in[2];  const float* sl_b = (const float*)d_in[3];
    const float* st_w = (const float*)d_in[4];  const float* st_b = (const float*)d_in[5];
    const float* seg_w = (const float*)d_in[6]; const float* seg_b = (const float*)d_in[7];
    const float* l1_w = (const float*)d_in[8];  const float* l1_b = (const float*)d_in[9];
    const float* l2_w = (const float*)d_in[10]; const float* l2_b = (const float*)d_in[11];
    const float* w_ih = (const float*)d_in[12]; const float* b_ih = (const float*)d_in[13];
    const float* w_hh = (const float*)d_in[14]; const float* b_hh = (const float*)d_in[15];
    const float* l4_w = (const float*)d_in[16]; const float* l4_b = (const float*)d_in[17];
    const float* l5_w = (const float*)d_in[18]; const float* l5_b = (const float*)d_in[19];
    const float* l6_w = (const float*)d_in[20]; const float* l6_b = (const float*)d_in[21];
    const float* l7_w = (const float*)d_in[22]; const float* l7_b = (const float*)d_in[23];

    char* ws = (char*)d_ws;
    float*  wsp   = (float*)(ws + WS_WSP);
    float*  ah    = (float*)(ws + WS_AH);
    float*  u527  = (float*)(ws + WS_U527);
    float*  biasT = (float*)(ws + WS_BIAS);
    float*  biasg = (float*)(ws + WS_BIASG);
    bf16_t* wc    = (bf16_t*)(ws + WS_WC);
    int*    flags = (int*)(ws + WS_FLAGS);
    bf16_t* hbuf  = (bf16_t*)(ws + WS_HBUF);

    float* out = (float*)d_out;

    hipMemsetAsync(flags, 0, 64*4*sizeof(int), stream);

    hipLaunchKernelGGL(k_head, dim3(1), dim3(512), 0, stream,
                       sl_w, sl_b, st_w, st_b, seg_b, l1_w, l1_b, l2_w, l2_b,
                       l4_w, l4_b, l5_w, l5_b, l6_w, l6_b, l7_w, l7_b,
                       wsp, ah, u527, biasT);
    hipLaunchKernelGGL(k_seg, dim3(5), dim3(256), 0, stream, seg_w, u527, wsp);
    hipLaunchKernelGGL(k_wc, dim3((1024*320 + 255)/256), dim3(256), 0, stream,
                       w_ih, b_ih, w_hh, b_hh, wc, biasg);
    hipLaunchKernelGGL(k_spatial, dim3(16384/4), dim3(256), 0, stream,
                       spatial, wsp, biasT, out);
    hipLaunchKernelGGL(k_lstm, dim3(256), dim3(256), 0, stream,
                       temporal, wc, biasg, ah, hbuf, flags, out);
}

// Round 7
// 2514.244 us; speedup vs baseline: 5.8114x; 5.8114x over previous
//
#include <hip/hip_runtime.h>
#include <hip/hip_bf16.h>
#include <math.h>

typedef __bf16 bf16_t;
typedef __bf16 bf16x8 __attribute__((ext_vector_type(8)));
typedef float  f32x4  __attribute__((ext_vector_type(4)));
typedef unsigned int uint32;

// ---------------- workspace layout (bytes) ----------------
#define WS_WSP    0        // 1297 f32
#define WS_AH     5248     // 256 f32
#define WS_U527   6272     // 527 f32
#define WS_BIAS   8384     // 1 f32
#define WS_BIASG  8448     // 1024 f32
#define WS_WC     12544    // 655360 B chunk-major weights (20 chunks x 32 KB)

__device__ __forceinline__ float sigmoidf_fast(float x) {
    return 1.f / (1.f + __expf(-x));
}
__device__ __forceinline__ float tanhf_fast(float x) {
    return 1.f - 2.f / (1.f + __expf(2.f * x));
}

// ---------------- head/spatial weight composition (tiny) ----------------
__global__ void k_head(const float* __restrict__ sl_w, const float* __restrict__ sl_b,
                       const float* __restrict__ st_w, const float* __restrict__ st_b,
                       const float* __restrict__ seg_b,
                       const float* __restrict__ l1_w, const float* __restrict__ l1_b,
                       const float* __restrict__ l2_w, const float* __restrict__ l2_b,
                       const float* __restrict__ l4_w, const float* __restrict__ l4_b,
                       const float* __restrict__ l5_w, const float* __restrict__ l5_b,
                       const float* __restrict__ l6_w, const float* __restrict__ l6_b,
                       const float* __restrict__ l7_w, const float* __restrict__ l7_b,
                       float* __restrict__ wsp, float* __restrict__ ah,
                       float* __restrict__ u527_out, float* __restrict__ bias_out) {
    __shared__ float v2[128], v3[256], aa[384], u256[256], u527[527];
    __shared__ float red[8];
    const int t = threadIdx.x;   // 512 threads

    if (t < 128) { float s = 0.f; for (int i = 0; i < 128; ++i) s += l7_w[i] * l6_w[i*128 + t]; v2[t] = s; }
    __syncthreads();
    if (t < 256) { float s = 0.f; for (int i = 0; i < 128; ++i) s += v2[i] * l5_w[i*256 + t]; v3[t] = s; }
    __syncthreads();
    if (t < 384) { float s = 0.f; for (int i = 0; i < 256; ++i) s += v3[i] * l4_w[i*384 + t]; aa[t] = s; }
    __syncthreads();
    if (t < 256) { float s = 0.f; for (int i = 0; i < 128; ++i) s += aa[i] * l2_w[i*256 + t]; u256[t] = s; }
    if (t < 256) ah[t] = aa[128 + t];
    __syncthreads();
    for (int j = t; j < 527; j += 512) {
        float s = 0.f;
        for (int i = 0; i < 256; ++i) s += u256[i] * l1_w[i*527 + j];
        u527[j] = s; u527_out[j] = s;
    }
    __syncthreads();
    if (t < 4)              { float s = 0.f; for (int i = 0; i < 2; ++i) s += u527[i]     * sl_w[i*4  + t];      wsp[t] = s; }
    else if (t < 16)        { int c = t - 4;  float s = 0.f; for (int i = 0; i < 8; ++i) s += u527[2+i] * st_w[i*12 + c]; wsp[t] = s; }
    else if (t < 21)        { wsp[1292 + (t - 16)] = u527[522 + (t - 16)]; }
    float p = 0.f;
    if (t < 128) p += l7_w[t] * l6_b[t] + v2[t] * l5_b[t] + aa[t] * l2_b[t];
    if (t < 256) p += v3[t] * l4_b[t] + u256[t] * l1_b[t];
    if (t < 2)   p += u527[t] * sl_b[t];
    if (t < 8)   p += u527[2 + t] * st_b[t];
    p += u527[10 + t] * seg_b[t];
    p += __shfl_xor(p, 1);  p += __shfl_xor(p, 2);  p += __shfl_xor(p, 4);
    p += __shfl_xor(p, 8);  p += __shfl_xor(p, 16); p += __shfl_xor(p, 32);
    if ((t & 63) == 0) red[t >> 6] = p;
    __syncthreads();
    if (t == 0) {
        float s = l7_b[0];
        for (int i = 0; i < 8; ++i) s += red[i];
        *bias_out = s;
    }
}

__global__ void k_seg(const float* __restrict__ seg_w, const float* __restrict__ u527,
                      float* __restrict__ wsp) {
    int j = blockIdx.x * 256 + threadIdx.x;
    if (j >= 1276) return;
    float s = 0.f;
    for (int i = 0; i < 512; ++i) s += u527[10 + i] * seg_w[i*1276 + j];
    wsp[16 + j] = s;
}

// Chunk-major weights for the LDS stream.
// Chunk ch = kk*2 + half (kk = K-slice of 32, half = N-half of 512 cols).
// Within chunk (32 KB): frag j in 0..31 at j*1024B; frag = 64 lanes x 16 B.
// Frag identity: gidx = half*32 + j ; wave w = gidx>>3, r = gidx&7, q=r>>1, u=r&1;
// orig ntile nt = q*16 + 2w + u; n = nt*16 + (lane&15); k = kk*32 + (lane>>4)*8 + e.
__global__ void k_wc2(const float* __restrict__ w_ih, const float* __restrict__ b_ih,
                      const float* __restrict__ w_hh, const float* __restrict__ b_hh,
                      bf16_t* __restrict__ wc2, float* __restrict__ biasg) {
    int idx = blockIdx.x * 256 + threadIdx.x;
    if (idx < 1024) biasg[idx] = b_ih[idx] + b_hh[idx];
    if (idx < 327680) {
        int e    = idx & 7;
        int lane = (idx >> 3) & 63;
        int j    = (idx >> 9) & 31;
        int ch   = idx >> 14;                 // 0..19
        int kk   = ch >> 1, half = ch & 1;
        int gidx = half*32 + j;
        int w = gidx >> 3, r = gidx & 7, q = r >> 1, u = r & 1;
        int nt = q*16 + 2*w + u;
        int n  = nt*16 + (lane & 15);
        int k  = kk*32 + ((lane >> 4) << 3) + e;
        float v = 0.f;
        if (k < 56)       v = w_ih[n*56 + k];
        else if (k >= 64) v = w_hh[n*256 + (k - 64)];
        wc2[idx] = (bf16_t)v;
    }
}

__global__ void k_spatial(const float* __restrict__ sp, const float* __restrict__ wsp,
                          const float* __restrict__ bias, float* __restrict__ out) {
    int row  = blockIdx.x * 4 + (threadIdx.x >> 6);
    int lane = threadIdx.x & 63;
    const float* rp = sp + (size_t)row * 1297;
    float s = 0.f;
    for (int k = lane; k < 1297; k += 64) s += rp[k] * wsp[k];
    s += __shfl_xor(s, 1);  s += __shfl_xor(s, 2);  s += __shfl_xor(s, 4);
    s += __shfl_xor(s, 8);  s += __shfl_xor(s, 16); s += __shfl_xor(s, 32);
    if (lane == 0) out[row] = s + bias[0];
}

// ---------------- LSTM v7: LDS-streamed weights (m97 pattern), 256 blocks x 64 rows --------
// 512 thr / 8 waves / 1 block/CU. Per step: C[64x1024] += A[64x320] * B, B streamed as
// 20 chunks of 32 KB through 3 rotating LDS slots, global_load_lds + vmcnt(4) + raw s_barrier.
// Wave w owns hd [32w,32w+32) for all gates; waves 0-3 compute even chunks (N-half 0),
// waves 4-7 odd chunks; all 8 cooperatively stage every chunk.
// At: flat [64][320] bf16, XOR-swizzled 16B slots (slot ^ (row&7)); cols 0..63 x(+pad), 64..319 h.
__launch_bounds__(512, 2)
__global__ void k_lstm(const float* __restrict__ temporal, const bf16_t* __restrict__ wc2,
                       const float* __restrict__ biasg, const float* __restrict__ ah,
                       float* __restrict__ out) {
    __shared__ bf16_t Wlds[3 * 16384];   // 98304 B
    __shared__ bf16_t At[64 * 320];      // 40960 B
    __shared__ float  Xf[64 * 56];       // 14336 B  (total 153600 B)
    char* Atb = (char*)At;

    const int tid  = threadIdx.x;
    const int lane = tid & 63;
    const int w    = tid >> 6;           // 0..7
    const int wg   = w & 3;
    const int hf   = w >> 2;             // wave's N-half
    const int l15  = lane & 15;
    const int l4q  = lane >> 4;          // 0..3
    const int row0 = blockIdx.x * 64;
    const int aswz = l15 & 7;

    float bias[8];
#pragma unroll
    for (int m = 0; m < 8; ++m) {
        int q = m >> 1, u = m & 1;
        bias[m] = biasg[q*256 + 32*w + 16*u + l15];
    }

    // x DMA per-thread source offsets (bytes): issue j = 2w+jj covers Xf bytes [j*1024, +1024)
    long xo0, xo1;
    {
        int b0 = (2*w + 0)*1024 + lane*16;
        int b1 = (2*w + 1)*1024 + lane*16;
        xo0 = (long)(b0/224)*21504 + (b0 % 224);
        xo1 = (long)(b1/224)*21504 + (b1 % 224);
    }
    const char* xbase = (const char*)(temporal + (size_t)row0 * 5376);

    auto stage_w = [&](int slot, int c) {
        const bf16_t* src = wc2 + (size_t)c*16384 + w*2048 + lane*8;
        bf16_t* dst = Wlds + slot*16384 + w*2048 + lane*8;
#pragma unroll
        for (int i = 0; i < 4; ++i)
            __builtin_amdgcn_global_load_lds(
                (const __attribute__((address_space(1))) uint32*)(src + i*512),
                (__attribute__((address_space(3))) uint32*)(dst + i*512), 16, 0, 0);
    };
    auto stage_x = [&](int tt) {
        if (w < 7) {
            const char* s0 = xbase + xo0 + (size_t)tt*224;
            const char* s1 = xbase + xo1 + (size_t)tt*224;
            float* d0 = Xf + (2*w)*256 + lane*4;
            float* d1 = Xf + (2*w+1)*256 + lane*4;
            __builtin_amdgcn_global_load_lds((const __attribute__((address_space(1))) uint32*)s0,
                                             (__attribute__((address_space(3))) uint32*)d0, 16, 0, 0);
            __builtin_amdgcn_global_load_lds((const __attribute__((address_space(1))) uint32*)s1,
                                             (__attribute__((address_space(3))) uint32*)d1, 16, 0, 0);
        }
    };
    auto conv_x = [&]() {
        int xr = tid >> 3, xs = tid & 7;
        bf16x8 v = (bf16x8){0,0,0,0,0,0,0,0};
        if (xs < 7) {
            const float* xf = Xf + xr*56 + xs*8;
            f32x4 a = *reinterpret_cast<const f32x4*>(xf);
            f32x4 b = *reinterpret_cast<const f32x4*>(xf + 4);
#pragma unroll
            for (int e = 0; e < 4; ++e) { v[e] = (bf16_t)a[e]; v[4+e] = (bf16_t)b[e]; }
        }
        *reinterpret_cast<bf16x8*>(Atb + xr*640 + ((xs ^ (xr & 7)) << 4)) = v;
    };

    // ---- prologue: stage chunks 0,1 and x_0; zero h region; convert x_0 ----
    stage_w(0, 0); stage_w(1, 1);
    stage_x(0);
#pragma unroll
    for (int it = 0; it < 4; ++it) {
        int i = tid + it*512;
        int zr = i >> 5, zs = 8 + (i & 31);
        *reinterpret_cast<bf16x8*>(Atb + zr*640 + ((zs ^ (zr & 7)) << 4)) =
            (bf16x8){0,0,0,0,0,0,0,0};
    }
    asm volatile("s_waitcnt vmcnt(0)" ::: "memory");
    __builtin_amdgcn_s_barrier();
    conv_x();
    asm volatile("s_waitcnt lgkmcnt(0)" ::: "memory");
    __builtin_amdgcn_s_barrier();

    f32x4 cst[8];    // c state [rt*2+u]
#pragma unroll
    for (int i = 0; i < 8; ++i) cst[i] = (f32x4){0.f,0.f,0.f,0.f};

    int sl = 0;      // LDS slot holding the current chunk
#pragma unroll 1
    for (int t = 0; t < 96; ++t) {
        f32x4 acc[4][8];
#pragma unroll
        for (int rt = 0; rt < 4; ++rt)
#pragma unroll
            for (int m = 0; m < 8; ++m)
                acc[rt][m] = (f32x4){bias[m], bias[m], bias[m], bias[m]};

#pragma unroll 1
        for (int c = 0; c < 20; ++c) {
            asm volatile("s_waitcnt vmcnt(4)" ::: "memory");   // chunk c landed (c+1 may fly)
            __builtin_amdgcn_s_barrier();
            int s2 = sl + 2; if (s2 >= 3) s2 -= 3;
            int c2 = c + 2;  if (c2 >= 20) c2 -= 20;
            stage_w(s2, c2);                                   // 2-deep prefetch
            if (c == 0 && t < 95) stage_x(t + 1);
            int kk = c >> 1;
            if ((c & 1) == hf) {
                bf16x8 af[4];
#pragma unroll
                for (int rt = 0; rt < 4; ++rt)
                    af[rt] = *reinterpret_cast<const bf16x8*>(
                        Atb + rt*10240 + l15*640 + (((4*kk + l4q) ^ aswz) << 4));
                const bf16_t* bb = Wlds + sl*16384 + wg*4096 + lane*8;
#pragma unroll
                for (int m = 0; m < 8; ++m) {
                    bf16x8 bf = *reinterpret_cast<const bf16x8*>(bb + m*512);
#pragma unroll
                    for (int rt = 0; rt < 4; ++rt)
                        acc[rt][m] = __builtin_amdgcn_mfma_f32_16x16x32_bf16(
                            af[rt], bf, acc[rt][m], 0, 0, 0);
                }
            }
            sl = sl + 1; if (sl >= 3) sl -= 3;
        }

        // ---- gates (regs only, before barrier) ----
        float hreg[4][2][4];
#pragma unroll
        for (int rt = 0; rt < 4; ++rt)
#pragma unroll
            for (int u = 0; u < 2; ++u)
#pragma unroll
                for (int e = 0; e < 4; ++e) {
                    float ig = sigmoidf_fast(acc[rt][0+u][e]);
                    float fg = sigmoidf_fast(acc[rt][2+u][e]);
                    float gt = tanhf_fast  (acc[rt][4+u][e]);
                    float og = sigmoidf_fast(acc[rt][6+u][e]);
                    float cn = fg * cst[rt*2+u][e] + ig * gt;
                    cst[rt*2+u][e] = cn;
                    hreg[rt][u][e] = og * tanhf_fast(cn);
                }

        __builtin_amdgcn_s_barrier();     // all At reads of this step done

        // ---- write h(t) into At (swizzled), convert x(t+1) ----
#pragma unroll
        for (int rt = 0; rt < 4; ++rt)
#pragma unroll
            for (int u = 0; u < 2; ++u) {
                int colslot = 8 + 4*w + 2*u + (l15 >> 3);
                int c7 = l15 & 7;
#pragma unroll
                for (int e = 0; e < 4; ++e) {
                    int row = 16*rt + l4q*4 + e;
                    *reinterpret_cast<unsigned short*>(
                        Atb + row*640 + ((colslot ^ (row & 7)) << 4) + c7*2) =
                        __builtin_bit_cast(unsigned short, (bf16_t)hreg[rt][u][e]);
                }
            }
        if (t < 95) {
            asm volatile("s_waitcnt vmcnt(8)" ::: "memory");   // x older than 8 newest stages
            conv_x();
        }
        asm volatile("s_waitcnt lgkmcnt(0)" ::: "memory");
        __builtin_amdgcn_s_barrier();
    }

    // ---- epilogue: out[row] += ah . h_T[row] ----
    {
        int r = tid >> 3, part = tid & 7;
        float s = 0.f;
#pragma unroll
        for (int jj = 0; jj < 32; ++jj) {
            int col = 64 + part*32 + jj;
            int cs = col >> 3;
            float hv = (float)*reinterpret_cast<const bf16_t*>(
                Atb + r*640 + ((cs ^ (r & 7)) << 4) + (col & 7)*2);
            s += ah[part*32 + jj] * hv;
        }
        s += __shfl_xor(s, 1); s += __shfl_xor(s, 2); s += __shfl_xor(s, 4);
        if (part == 0) out[row0 + r] += s;
    }
}

// ---------------- launch ----------------
extern "C" void kernel_launch(void* const* d_in, const int* in_sizes, int n_in,
                              void* d_out, int out_size, void* d_ws, size_t ws_size,
                              hipStream_t stream) {
    const float* spatial  = (const float*)d_in[0];
    const float* temporal = (const float*)d_in[1];
    const float* sl_w = (const float*)d_in[2];  const float* sl_b = (const float*)d_in[3];
    const float* st_w = (const float*)d_in[4];  const float* st_b = (const float*)d_in[5];
    const float* seg_w = (const float*)d_in[6]; const float* seg_b = (const float*)d_in[7];
    const float* l1_w = (const float*)d_in[8];  const float* l1_b = (const float*)d_in[9];
    const float* l2_w = (const float*)d_in[10]; const float* l2_b = (const float*)d_in[11];
    const float* w_ih = (const float*)d_in[12]; const float* b_ih = (const float*)d_in[13];
    const float* w_hh = (const float*)d_in[14]; const float* b_hh = (const float*)d_in[15];
    const float* l4_w = (const float*)d_in[16]; const float* l4_b = (const float*)d_in[17];
    const float* l5_w = (const float*)d_in[18]; const float* l5_b = (const float*)d_in[19];
    const float* l6_w = (const float*)d_in[20]; const float* l6_b = (const float*)d_in[21];
    const float* l7_w = (const float*)d_in[22]; const float* l7_b = (const float*)d_in[23];

    char* ws = (char*)d_ws;
    float*  wsp   = (float*)(ws + WS_WSP);
    float*  ah    = (float*)(ws + WS_AH);
    float*  u527  = (float*)(ws + WS_U527);
    float*  biasT = (float*)(ws + WS_BIAS);
    float*  biasg = (float*)(ws + WS_BIASG);
    bf16_t* wc2   = (bf16_t*)(ws + WS_WC);

    float* out = (float*)d_out;

    hipLaunchKernelGGL(k_head, dim3(1), dim3(512), 0, stream,
                       sl_w, sl_b, st_w, st_b, seg_b, l1_w, l1_b, l2_w, l2_b,
                       l4_w, l4_b, l5_w, l5_b, l6_w, l6_b, l7_w, l7_b,
                       wsp, ah, u527, biasT);
    hipLaunchKernelGGL(k_seg, dim3(5), dim3(256), 0, stream, seg_w, u527, wsp);
    hipLaunchKernelGGL(k_wc2, dim3(1280), dim3(256), 0, stream,
                       w_ih, b_ih, w_hh, b_hh, wc2, biasg);
    hipLaunchKernelGGL(k_spatial, dim3(16384/4), dim3(256), 0, stream,
                       spatial, wsp, biasT, out);
    hipLaunchKernelGGL(k_lstm, dim3(256), dim3(512), 0, stream,
                       temporal, wc2, biasg, ah, out);
}